// Round 4
// baseline (628.213 us; speedup 1.0000x reference)
//
#include <hip/hip_runtime.h>
#include <hip/hip_bf16.h>

// Model: one_hot -> 3x Conv2D(5,(4,4),(1,2),SAME) -> [B,S=1024,D=20]
//        -> 3x causal self-attention -> flatten -> 3x Dense(10)
// B=64, L=8192, S=1024, D=20. All fp32 except int32 inputs.

#define B_ 64
#define L_ 8192
#define S_ 1024
#define D_ 20

// ---------------- conv1: one-hot input, CI=1 ----------------
__global__ __launch_bounds__(256) void conv1_kernel(
    const int* __restrict__ inp, const float* __restrict__ W,
    const float* __restrict__ Bi, float* __restrict__ out) {
  __shared__ float ws[80];
  __shared__ float bs[5];
  if (threadIdx.x < 80) ws[threadIdx.x] = W[threadIdx.x];
  if (threadIdx.x < 5)  bs[threadIdx.x] = Bi[threadIdx.x];
  __syncthreads();
  int idx = blockIdx.x * 256 + threadIdx.x;   // (b, wo), wo in [0,4096)
  int b  = idx >> 12;
  int wo = idx & 4095;
  float acc[4][5];
#pragma unroll
  for (int h = 0; h < 4; ++h)
#pragma unroll
    for (int c = 0; c < 5; ++c) acc[h][c] = bs[c];
  const int* ib = inp + (size_t)b * L_;
#pragma unroll
  for (int kw = 0; kw < 4; ++kw) {
    int wi = 2 * wo - 1 + kw;
    if (wi >= 0 && wi < L_) {
      int v = ib[wi];
#pragma unroll
      for (int h = 0; h < 4; ++h) {
        int kh = v - h + 1;                   // hi = h-1+kh == v
        if (kh >= 0 && kh < 4) {
#pragma unroll
          for (int c = 0; c < 5; ++c) acc[h][c] += ws[(kh * 4 + kw) * 5 + c];
        }
      }
    }
  }
  float* ob = out + (size_t)b * 4 * 4096 * 5;
#pragma unroll
  for (int h = 0; h < 4; ++h)
#pragma unroll
    for (int c = 0; c < 5; ++c) ob[(h * 4096 + wo) * 5 + c] = acc[h][c];
}

// ---------------- conv2/conv3: CI=5, CO=5, 2 outputs/thread ----------------
// vector path: 9 aligned float4 loads per input row (instead of 20 scalar).
template <int WIN, bool TRANS>
__global__ __launch_bounds__(256) void conv5_kernel(
    const float* __restrict__ in, const float* __restrict__ W,
    const float* __restrict__ Bi, float* __restrict__ out) {
  constexpr int WOUT = WIN / 2;
  constexpr int NU   = WOUT / 2;       // 2 outputs per thread
  __shared__ float ws[400];
  __shared__ float bs[5];
  for (int j = threadIdx.x; j < 400; j += 256) ws[j] = W[j];
  if (threadIdx.x < 5) bs[threadIdx.x] = Bi[threadIdx.x];
  __syncthreads();
  int idx = blockIdx.x * 256 + threadIdx.x;   // (b, u)
  int b = idx / NU;
  int u = idx % NU;
  // outputs wo = 2u, 2u+1 need wi in [4u-1, 4u+4] -> 6 positions x 5 ci
  float val[4][6][5];
  if (u > 0 && u < NU - 1) {
#pragma unroll
    for (int hi = 0; hi < 4; ++hi) {
      const float4* src = (const float4*)(in + ((size_t)b * 4 + hi) * WIN * 5 + (20 * u - 8));
      float st[36];
#pragma unroll
      for (int j = 0; j < 9; ++j) {
        float4 t = src[j];
        st[4*j] = t.x; st[4*j+1] = t.y; st[4*j+2] = t.z; st[4*j+3] = t.w;
      }
#pragma unroll
      for (int pos = 0; pos < 6; ++pos)
#pragma unroll
        for (int ci = 0; ci < 5; ++ci) val[hi][pos][ci] = st[3 + pos * 5 + ci];
    }
  } else {
#pragma unroll
    for (int hi = 0; hi < 4; ++hi) {
      const float* ir = in + ((size_t)b * 4 + hi) * WIN * 5;
#pragma unroll
      for (int pos = 0; pos < 6; ++pos) {
        int wi = 4 * u - 1 + pos;
        bool ok = (wi >= 0 && wi < WIN);
#pragma unroll
        for (int ci = 0; ci < 5; ++ci) val[hi][pos][ci] = ok ? ir[wi * 5 + ci] : 0.f;
      }
    }
  }
  float acc[2][4][5];
#pragma unroll
  for (int o = 0; o < 2; ++o)
#pragma unroll
    for (int h = 0; h < 4; ++h)
#pragma unroll
      for (int c = 0; c < 5; ++c) acc[o][h][c] = bs[c];
#pragma unroll
  for (int kh = 0; kh < 4; ++kh)
#pragma unroll
    for (int kw = 0; kw < 4; ++kw)
#pragma unroll
      for (int ci = 0; ci < 5; ++ci) {
        const float* wp = ws + ((kh * 4 + kw) * 5 + ci) * 5;
        float w0 = wp[0], w1 = wp[1], w2 = wp[2], w3 = wp[3], w4 = wp[4];
#pragma unroll
        for (int h = 0; h < 4; ++h) {
          int hi = h - 1 + kh;
          if (hi >= 0 && hi < 4) {
#pragma unroll
            for (int o = 0; o < 2; ++o) {
              float x = val[hi][2 * o + kw][ci];
              acc[o][h][0] += w0 * x; acc[o][h][1] += w1 * x; acc[o][h][2] += w2 * x;
              acc[o][h][3] += w3 * x; acc[o][h][4] += w4 * x;
            }
          }
        }
      }
#pragma unroll
  for (int o = 0; o < 2; ++o) {
    int wo = 2 * u + o;
    if (TRANS) {
      float* ob = out + ((size_t)b * WOUT + wo) * 20;
#pragma unroll
      for (int h = 0; h < 4; ++h)
#pragma unroll
        for (int c = 0; c < 5; ++c) ob[h * 5 + c] = acc[o][h][c];
    } else {
      float* ob = out + (size_t)b * 4 * WOUT * 5;
#pragma unroll
      for (int h = 0; h < 4; ++h)
#pragma unroll
        for (int c = 0; c < 5; ++c) ob[(h * WOUT + wo) * 5 + c] = acc[o][h][c];
    }
  }
}

// ---------------- Q/K/V projection, weights staged in LDS ----------------
__global__ __launch_bounds__(256) void proj_kernel(
    const float* __restrict__ X,
    const float* __restrict__ Kw, const float* __restrict__ Qw,
    const float* __restrict__ Vw,
    float* __restrict__ Qo, float* __restrict__ Ko, float* __restrict__ Vo) {
  __shared__ float kw[400], qw[400], vw[400];
  for (int j = threadIdx.x; j < 400; j += 256) {
    kw[j] = Kw[j]; qw[j] = Qw[j]; vw[j] = Vw[j];
  }
  __syncthreads();
  int r = blockIdx.x * 256 + threadIdx.x;
  const float4* xr4 = (const float4*)(X + (size_t)r * D_);
  float x[D_];
#pragma unroll
  for (int i = 0; i < 5; ++i) {
    float4 t = xr4[i];
    x[4*i] = t.x; x[4*i+1] = t.y; x[4*i+2] = t.z; x[4*i+3] = t.w;
  }
  float q[D_], k[D_], v[D_];
#pragma unroll
  for (int j = 0; j < D_; ++j) { q[j] = 0.f; k[j] = 0.f; v[j] = 0.f; }
#pragma unroll
  for (int i = 0; i < D_; ++i) {
#pragma unroll
    for (int j = 0; j < D_; ++j) {
      q[j] += x[i] * qw[i * D_ + j];
      k[j] += x[i] * kw[i * D_ + j];
      v[j] += x[i] * vw[i * D_ + j];
    }
  }
  const float sc = 0.22360679774997896f;  // 1/sqrt(20)
  float4* qo = (float4*)(Qo + (size_t)r * D_);
  float4* ko = (float4*)(Ko + (size_t)r * D_);
  float4* vo = (float4*)(Vo + (size_t)r * D_);
#pragma unroll
  for (int i = 0; i < 5; ++i) {
    qo[i] = make_float4(q[4*i]*sc, q[4*i+1]*sc, q[4*i+2]*sc, q[4*i+3]*sc);
    ko[i] = make_float4(k[4*i],    k[4*i+1],    k[4*i+2],    k[4*i+3]);
    vo[i] = make_float4(v[4*i],    v[4*i+1],    v[4*i+2],    v[4*i+3]);
  }
}

// ---------------- causal attention ----------------
// R2-proven skeleton (4-lane t-split, 2-round butterfly) + R=2 rows/thread:
// 128-row strips; c = tid&3 splits t (t%4==c); group g = tid>>2 owns rows
// (q0+2g, q0+2g+1) so each K/V LDS read serves 2 (q,t) pairs. Strips are
// 128-aligned -> every tile full (iend uniform). Scores tiny -> softmax
// without max-subtraction is exact; lane merge = 2-round butterfly add.
#define TT_ 128
__global__ __launch_bounds__(256) void attn_kernel(
    const float* __restrict__ Q, const float* __restrict__ K,
    const float* __restrict__ V, float* __restrict__ out) {
  const int b     = blockIdx.y;
  const int strip = 7 - blockIdx.x;       // heavy strips first (LPT)
  const int q0    = strip * 128;
  const int tid   = threadIdx.x;
  const int c     = tid & 3;              // t-lane within group
  const int g     = tid >> 2;             // group 0..63
  const int qr    = q0 + 2 * g;           // rows qr, qr+1
  __shared__ float kt[TT_ * D_];
  __shared__ float vt[TT_ * D_];
  const size_t base = (size_t)b * S_ * D_;
  float qv0[D_], qv1[D_], O0[D_], O1[D_];
  {
    const float4* Qa = (const float4*)(Q + base + (size_t)qr * D_);
    const float4* Qb = (const float4*)(Q + base + (size_t)(qr + 1) * D_);
#pragma unroll
    for (int i = 0; i < 5; ++i) {
      float4 ta = Qa[i], tb = Qb[i];
      qv0[4*i] = ta.x; qv0[4*i+1] = ta.y; qv0[4*i+2] = ta.z; qv0[4*i+3] = ta.w;
      qv1[4*i] = tb.x; qv1[4*i+1] = tb.y; qv1[4*i+2] = tb.z; qv1[4*i+3] = tb.w;
    }
  }
#pragma unroll
  for (int d = 0; d < D_; ++d) { O0[d] = 0.f; O1[d] = 0.f; }
  float l0 = 0.f, l1 = 0.f;
  const int nt = q0 + 128;                // multiple of TT_ -> tiles always full
  float4* kd4 = (float4*)kt;
  float4* vd4 = (float4*)vt;
  for (int t0 = 0; t0 < nt; t0 += TT_) {
    __syncthreads();
    const float4* ksrc = (const float4*)(K + base) + t0 * 5;
    const float4* vsrc = (const float4*)(V + base) + t0 * 5;
    for (int j = tid; j < TT_ * 5; j += 256) {
      kd4[j] = ksrc[j];
      vd4[j] = vsrc[j];
    }
    __syncthreads();
#pragma unroll 2
    for (int i = 0; i < TT_ / 4; ++i) {
      const int tl = 4 * i + c;
      const float* kr = kt + tl * D_;
      float s0 = 0.f, s1 = 0.f;
#pragma unroll
      for (int d = 0; d < D_; ++d) { float kk = kr[d]; s0 += qv0[d] * kk; s1 += qv1[d] * kk; }
      const int t = t0 + tl;
      float p0 = (t <= qr)     ? __expf(s0) : 0.f;
      float p1 = (t <= qr + 1) ? __expf(s1) : 0.f;
      l0 += p0; l1 += p1;
      const float* vr = vt + tl * D_;
#pragma unroll
      for (int d = 0; d < D_; ++d) { float vv = vr[d]; O0[d] += p0 * vv; O1[d] += p1 * vv; }
    }
  }
  // merge partials across the 4 t-lanes of each group (R2-proven structure)
#pragma unroll
  for (int m = 1; m <= 2; m <<= 1) {
    l0 += __shfl_xor(l0, m, 64);
    l1 += __shfl_xor(l1, m, 64);
#pragma unroll
    for (int d = 0; d < D_; ++d) {
      O0[d] += __shfl_xor(O0[d], m, 64);
      O1[d] += __shfl_xor(O1[d], m, 64);
    }
  }
  const float i0 = 1.f / l0, i1 = 1.f / l1;
  float* o0 = out + base + (size_t)qr * D_ + c * 5;
  float* o1 = out + base + (size_t)(qr + 1) * D_ + c * 5;
#pragma unroll
  for (int j = 0; j < 5; ++j) {
    o0[j] = O0[c * 5 + j] * i0;
    o1[j] = O1[c * 5 + j] * i1;
  }
}

// ---------------- dense head: stage 1 (partials) ----------------
__global__ __launch_bounds__(256) void dense1_partial(
    const float* __restrict__ X,   // [64, 20480]
    const float* __restrict__ W1,  // [20480, 10]
    float* __restrict__ part) {    // [64, 4, 10]
  const int b = blockIdx.x;
  const int s = blockIdx.y;
  const float* xb = X + (size_t)b * 20480 + s * 5120;
  const float* wb = W1 + (size_t)s * 5120 * 10;
  float acc[10];
#pragma unroll
  for (int j = 0; j < 10; ++j) acc[j] = 0.f;
  for (int i = threadIdx.x; i < 5120; i += 256) {
    float v = xb[i];
    const float* wr = wb + i * 10;
#pragma unroll
    for (int j = 0; j < 10; ++j) acc[j] += v * wr[j];
  }
  __shared__ float red[256][10];
#pragma unroll
  for (int j = 0; j < 10; ++j) red[threadIdx.x][j] = acc[j];
  __syncthreads();
  for (int off = 128; off > 0; off >>= 1) {
    if (threadIdx.x < (unsigned)off) {
#pragma unroll
      for (int j = 0; j < 10; ++j) red[threadIdx.x][j] += red[threadIdx.x + off][j];
    }
    __syncthreads();
  }
  if (threadIdx.x < 10) part[(b * 4 + s) * 10 + threadIdx.x] = red[0][threadIdx.x];
}

// ---------------- dense head: stage 2 (combine + dense2/3) ----------------
__global__ __launch_bounds__(64) void dense_final(
    const float* __restrict__ part,
    const float* __restrict__ B1,
    const float* __restrict__ W2, const float* __restrict__ B2,
    const float* __restrict__ W3, const float* __restrict__ B3,
    float* __restrict__ out) {
  const int b = blockIdx.x;
  __shared__ float y1[10], y2[10];
  if (threadIdx.x < 10) {
    int j = threadIdx.x;
    y1[j] = part[(b*4+0)*10 + j] + part[(b*4+1)*10 + j] +
            part[(b*4+2)*10 + j] + part[(b*4+3)*10 + j] + B1[j];
  }
  __syncthreads();
  if (threadIdx.x < 10) {
    int j = threadIdx.x;
    float s = B2[j];
#pragma unroll
    for (int i = 0; i < 10; ++i) s += y1[i] * W2[i * 10 + j];
    y2[j] = s;
  }
  __syncthreads();
  if (threadIdx.x < 10) {
    int j = threadIdx.x;
    float s = B3[j];
#pragma unroll
    for (int i = 0; i < 10; ++i) s += y2[i] * W3[i * 10 + j];
    out[b * 10 + j] = s;
  }
}

extern "C" void kernel_launch(void* const* d_in, const int* in_sizes, int n_in,
                              void* d_out, int out_size, void* d_ws, size_t ws_size,
                              hipStream_t stream) {
  const int*   inp = (const int*)d_in[0];
  const float* cw1 = (const float*)d_in[1];
  const float* cb1 = (const float*)d_in[2];
  const float* cw2 = (const float*)d_in[3];
  const float* cb2 = (const float*)d_in[4];
  const float* cw3 = (const float*)d_in[5];
  const float* cb3 = (const float*)d_in[6];
  const float* a1K = (const float*)d_in[7];
  const float* a1Q = (const float*)d_in[8];
  const float* a1V = (const float*)d_in[9];
  const float* a2K = (const float*)d_in[10];
  const float* a2Q = (const float*)d_in[11];
  const float* a2V = (const float*)d_in[12];
  const float* a3K = (const float*)d_in[13];
  const float* a3Q = (const float*)d_in[14];
  const float* a3V = (const float*)d_in[15];
  const float* dw1 = (const float*)d_in[16];
  const float* db1 = (const float*)d_in[17];
  const float* dw2 = (const float*)d_in[18];
  const float* db2 = (const float*)d_in[19];
  const float* dw3 = (const float*)d_in[20];
  const float* db3 = (const float*)d_in[21];
  float* outp = (float*)d_out;

  // workspace layout (floats); total 9,175,040 floats = 36.7 MB
  float* wsf  = (float*)d_ws;
  float* c1   = wsf;                 // [B,4,4096,5]  5,242,880 floats
  float* c2   = wsf + 5242880;       // [B,4,2048,5]  2,621,440 floats
  float* x    = wsf + 7864320;       // [B,S,20]      1,310,720 floats
  float* q    = wsf;                 // reuse c1 after conv2
  float* k    = wsf + 1310720;
  float* v    = wsf + 2621440;
  float* part = wsf + 3932160;       // [64,4,10] = 2,560 floats
  float* o    = c2;                  // reuse c2 after conv3

  conv1_kernel<<<1024, 256, 0, stream>>>(inp, cw1, cb1, c1);
  conv5_kernel<4096, false><<<256, 256, 0, stream>>>(c1, cw2, cb2, c2);
  conv5_kernel<2048, true><<<128, 256, 0, stream>>>(c2, cw3, cb3, x);

  proj_kernel<<<256, 256, 0, stream>>>(x, a1K, a1Q, a1V, q, k, v);
  attn_kernel<<<dim3(8, 64), 256, 0, stream>>>(q, k, v, o);

  proj_kernel<<<256, 256, 0, stream>>>(o, a2K, a2Q, a2V, q, k, v);
  attn_kernel<<<dim3(8, 64), 256, 0, stream>>>(q, k, v, x);

  proj_kernel<<<256, 256, 0, stream>>>(x, a3K, a3Q, a3V, q, k, v);
  attn_kernel<<<dim3(8, 64), 256, 0, stream>>>(q, k, v, o);

  dense1_partial<<<dim3(64, 4), 256, 0, stream>>>(o, dw1, part);
  dense_final<<<64, 64, 0, stream>>>(part, db1, dw2, db2, dw3, db3, outp);
}

// Round 5
// 555.103 us; speedup vs baseline: 1.1317x; 1.1317x over previous
//
#include <hip/hip_runtime.h>
#include <hip/hip_bf16.h>

// Model: one_hot -> 3x Conv2D(5,(4,4),(1,2),SAME) -> [B,S=1024,D=20]
//        -> 3x causal self-attention -> flatten -> 3x Dense(10)
// B=64, L=8192, S=1024, D=20. All fp32 except int32 inputs.

#define B_ 64
#define L_ 8192
#define S_ 1024
#define D_ 20

// ---------------- conv1: one-hot input, CI=1 ----------------
__global__ __launch_bounds__(256) void conv1_kernel(
    const int* __restrict__ inp, const float* __restrict__ W,
    const float* __restrict__ Bi, float* __restrict__ out) {
  __shared__ float ws[80];
  __shared__ float bs[5];
  if (threadIdx.x < 80) ws[threadIdx.x] = W[threadIdx.x];
  if (threadIdx.x < 5)  bs[threadIdx.x] = Bi[threadIdx.x];
  __syncthreads();
  int idx = blockIdx.x * 256 + threadIdx.x;   // (b, wo), wo in [0,4096)
  int b  = idx >> 12;
  int wo = idx & 4095;
  float acc[4][5];
#pragma unroll
  for (int h = 0; h < 4; ++h)
#pragma unroll
    for (int c = 0; c < 5; ++c) acc[h][c] = bs[c];
  const int* ib = inp + (size_t)b * L_;
#pragma unroll
  for (int kw = 0; kw < 4; ++kw) {
    int wi = 2 * wo - 1 + kw;
    if (wi >= 0 && wi < L_) {
      int v = ib[wi];
#pragma unroll
      for (int h = 0; h < 4; ++h) {
        int kh = v - h + 1;                   // hi = h-1+kh == v
        if (kh >= 0 && kh < 4) {
#pragma unroll
          for (int c = 0; c < 5; ++c) acc[h][c] += ws[(kh * 4 + kw) * 5 + c];
        }
      }
    }
  }
  float* ob = out + (size_t)b * 4 * 4096 * 5;
#pragma unroll
  for (int h = 0; h < 4; ++h)
#pragma unroll
    for (int c = 0; c < 5; ++c) ob[(h * 4096 + wo) * 5 + c] = acc[h][c];
}

// ---------------- conv2/conv3: CI=5, CO=5 (R2-proven version) ----------------
template <int WIN, bool TRANS>
__global__ __launch_bounds__(256) void conv5_kernel(
    const float* __restrict__ in, const float* __restrict__ W,
    const float* __restrict__ Bi, float* __restrict__ out) {
  constexpr int WOUT = WIN / 2;
  __shared__ float ws[400];
  __shared__ float bs[5];
  for (int j = threadIdx.x; j < 400; j += 256) ws[j] = W[j];
  if (threadIdx.x < 5) bs[threadIdx.x] = Bi[threadIdx.x];
  __syncthreads();
  int idx = blockIdx.x * 256 + threadIdx.x;   // (b, wo)
  int b  = idx / WOUT;
  int wo = idx % WOUT;
  float val[4][4][5];
#pragma unroll
  for (int hi = 0; hi < 4; ++hi) {
    const float* ir = in + ((size_t)b * 4 + hi) * WIN * 5;
#pragma unroll
    for (int kw = 0; kw < 4; ++kw) {
      int wi = 2 * wo - 1 + kw;
      bool ok = (wi >= 0 && wi < WIN);
#pragma unroll
      for (int ci = 0; ci < 5; ++ci) val[hi][kw][ci] = ok ? ir[wi * 5 + ci] : 0.f;
    }
  }
  float acc[4][5];
#pragma unroll
  for (int h = 0; h < 4; ++h)
#pragma unroll
    for (int c = 0; c < 5; ++c) acc[h][c] = bs[c];
#pragma unroll
  for (int kh = 0; kh < 4; ++kh)
#pragma unroll
    for (int kw = 0; kw < 4; ++kw)
#pragma unroll
      for (int ci = 0; ci < 5; ++ci) {
        const float* wp = ws + ((kh * 4 + kw) * 5 + ci) * 5;
        float w0 = wp[0], w1 = wp[1], w2 = wp[2], w3 = wp[3], w4 = wp[4];
#pragma unroll
        for (int h = 0; h < 4; ++h) {
          int hi = h - 1 + kh;
          if (hi >= 0 && hi < 4) {
            float x = val[hi][kw][ci];
            acc[h][0] += w0 * x; acc[h][1] += w1 * x; acc[h][2] += w2 * x;
            acc[h][3] += w3 * x; acc[h][4] += w4 * x;
          }
        }
      }
  if (TRANS) {
    float* ob = out + ((size_t)b * WOUT + wo) * 20;
#pragma unroll
    for (int h = 0; h < 4; ++h)
#pragma unroll
      for (int c = 0; c < 5; ++c) ob[h * 5 + c] = acc[h][c];
  } else {
    float* ob = out + (size_t)b * 4 * WOUT * 5;
#pragma unroll
    for (int h = 0; h < 4; ++h)
#pragma unroll
      for (int c = 0; c < 5; ++c) ob[(h * WOUT + wo) * 5 + c] = acc[h][c];
  }
}

// ---------------- Q/K/V projection, weights staged in LDS ----------------
__global__ __launch_bounds__(256) void proj_kernel(
    const float* __restrict__ X,
    const float* __restrict__ Kw, const float* __restrict__ Qw,
    const float* __restrict__ Vw,
    float* __restrict__ Qo, float* __restrict__ Ko, float* __restrict__ Vo) {
  __shared__ float kw[400], qw[400], vw[400];
  for (int j = threadIdx.x; j < 400; j += 256) {
    kw[j] = Kw[j]; qw[j] = Qw[j]; vw[j] = Vw[j];
  }
  __syncthreads();
  int r = blockIdx.x * 256 + threadIdx.x;
  const float4* xr4 = (const float4*)(X + (size_t)r * D_);
  float x[D_];
#pragma unroll
  for (int i = 0; i < 5; ++i) {
    float4 t = xr4[i];
    x[4*i] = t.x; x[4*i+1] = t.y; x[4*i+2] = t.z; x[4*i+3] = t.w;
  }
  float q[D_], k[D_], v[D_];
#pragma unroll
  for (int j = 0; j < D_; ++j) { q[j] = 0.f; k[j] = 0.f; v[j] = 0.f; }
#pragma unroll
  for (int i = 0; i < D_; ++i) {
#pragma unroll
    for (int j = 0; j < D_; ++j) {
      q[j] += x[i] * qw[i * D_ + j];
      k[j] += x[i] * kw[i * D_ + j];
      v[j] += x[i] * vw[i * D_ + j];
    }
  }
  const float sc = 0.22360679774997896f;  // 1/sqrt(20)
  float4* qo = (float4*)(Qo + (size_t)r * D_);
  float4* ko = (float4*)(Ko + (size_t)r * D_);
  float4* vo = (float4*)(Vo + (size_t)r * D_);
#pragma unroll
  for (int i = 0; i < 5; ++i) {
    qo[i] = make_float4(q[4*i]*sc, q[4*i+1]*sc, q[4*i+2]*sc, q[4*i+3]*sc);
    ko[i] = make_float4(k[4*i],    k[4*i+1],    k[4*i+2],    k[4*i+3]);
    vo[i] = make_float4(v[4*i],    v[4*i+1],    v[4*i+2],    v[4*i+3]);
  }
}

// ---------------- causal attention: paired-strip, uniform-work blocks ----
// 16 strips of 64 q-rows. Block j handles strips j (short) and 15-j (long):
// combined t-work = 17 tile-units for EVERY block -> balanced on any
// block->CU assignment. Waves 0-1 = short strip, waves 2-3 = long strip
// (wave-aligned halves). Both halves share one K/V LDS staging; short-half
// waves keep staging + barriers after their compute ends (uniform loop
// bound -> no deadlock). R=2 rows/thread: c=tid&3 splits t, each lane owns
// 2 adjacent rows so every K/V LDS read serves 2 (q,t) pairs. Scores tiny
// -> softmax without max-subtraction exact; merge = 2-round butterfly.
#define TT_ 128
__global__ __launch_bounds__(256) void attn_kernel(
    const float* __restrict__ Q, const float* __restrict__ K,
    const float* __restrict__ V, float* __restrict__ out) {
  const int b    = blockIdx.y;
  const int j    = blockIdx.x;            // 0..7
  const int tid  = threadIdx.x;
  const int c    = tid & 3;               // t-lane within group
  const int g    = tid >> 2;              // group 0..63
  const int half = g >> 5;                // 0: strip j, 1: strip 15-j
  const int gl   = g & 31;
  const int strip = half ? (15 - j) : j;
  const int q0   = strip * 64;
  const int qr   = q0 + 2 * gl;           // rows qr, qr+1
  const int myNt = q0 + 64;               // this half needs t < myNt
  const int ntMax = (16 - j) * 64;        // long strip's need (uniform bound)
  __shared__ float kt[TT_ * D_];
  __shared__ float vt[TT_ * D_];
  const size_t base = (size_t)b * S_ * D_;
  float qv0[D_], qv1[D_], O0[D_], O1[D_];
  {
    const float4* Qa = (const float4*)(Q + base + (size_t)qr * D_);
    const float4* Qb = (const float4*)(Q + base + (size_t)(qr + 1) * D_);
#pragma unroll
    for (int i = 0; i < 5; ++i) {
      float4 ta = Qa[i], tb = Qb[i];
      qv0[4*i] = ta.x; qv0[4*i+1] = ta.y; qv0[4*i+2] = ta.z; qv0[4*i+3] = ta.w;
      qv1[4*i] = tb.x; qv1[4*i+1] = tb.y; qv1[4*i+2] = tb.z; qv1[4*i+3] = tb.w;
    }
  }
#pragma unroll
  for (int d = 0; d < D_; ++d) { O0[d] = 0.f; O1[d] = 0.f; }
  float l0 = 0.f, l1 = 0.f;
  float4* kd4 = (float4*)kt;
  float4* vd4 = (float4*)vt;
  for (int t0 = 0; t0 < ntMax; t0 += TT_) {
    __syncthreads();
    // stage rows [t0, t0+TT_); t0+TT_ <= 1024 always (see analysis)
    const float4* ksrc = (const float4*)(K + base) + t0 * 5;
    const float4* vsrc = (const float4*)(V + base) + t0 * 5;
    for (int jj = tid; jj < TT_ * 5; jj += 256) {
      kd4[jj] = ksrc[jj];
      vd4[jj] = vsrc[jj];
    }
    __syncthreads();
    const int rem = myNt - t0;            // uniform per wave (halves wave-aligned)
    if (rem > 0) {
      const int iend = (rem > TT_ ? TT_ : rem) >> 2;
      for (int i = 0; i < iend; ++i) {
        const int tl = 4 * i + c;
        const float* kr = kt + tl * D_;
        float s0 = 0.f, s1 = 0.f;
#pragma unroll
        for (int d = 0; d < D_; ++d) { float kk = kr[d]; s0 += qv0[d] * kk; s1 += qv1[d] * kk; }
        const int t = t0 + tl;
        float p0 = (t <= qr)     ? __expf(s0) : 0.f;
        float p1 = (t <= qr + 1) ? __expf(s1) : 0.f;
        l0 += p0; l1 += p1;
        const float* vr = vt + tl * D_;
#pragma unroll
        for (int d = 0; d < D_; ++d) { float vv = vr[d]; O0[d] += p0 * vv; O1[d] += p1 * vv; }
      }
    }
  }
  // merge partials across the 4 t-lanes of each group
#pragma unroll
  for (int m = 1; m <= 2; m <<= 1) {
    l0 += __shfl_xor(l0, m, 64);
    l1 += __shfl_xor(l1, m, 64);
#pragma unroll
    for (int d = 0; d < D_; ++d) {
      O0[d] += __shfl_xor(O0[d], m, 64);
      O1[d] += __shfl_xor(O1[d], m, 64);
    }
  }
  const float i0 = 1.f / l0, i1 = 1.f / l1;
  float* o0 = out + base + (size_t)qr * D_ + c * 5;
  float* o1 = out + base + (size_t)(qr + 1) * D_ + c * 5;
#pragma unroll
  for (int jj = 0; jj < 5; ++jj) {
    o0[jj] = O0[c * 5 + jj] * i0;
    o1[jj] = O1[c * 5 + jj] * i1;
  }
}

// ---------------- dense head: stage 1 (partials) ----------------
__global__ __launch_bounds__(256) void dense1_partial(
    const float* __restrict__ X,   // [64, 20480]
    const float* __restrict__ W1,  // [20480, 10]
    float* __restrict__ part) {    // [64, 4, 10]
  const int b = blockIdx.x;
  const int s = blockIdx.y;
  const float* xb = X + (size_t)b * 20480 + s * 5120;
  const float* wb = W1 + (size_t)s * 5120 * 10;
  float acc[10];
#pragma unroll
  for (int j = 0; j < 10; ++j) acc[j] = 0.f;
  for (int i = threadIdx.x; i < 5120; i += 256) {
    float v = xb[i];
    const float* wr = wb + i * 10;
#pragma unroll
    for (int j = 0; j < 10; ++j) acc[j] += v * wr[j];
  }
  __shared__ float red[256][10];
#pragma unroll
  for (int j = 0; j < 10; ++j) red[threadIdx.x][j] = acc[j];
  __syncthreads();
  for (int off = 128; off > 0; off >>= 1) {
    if (threadIdx.x < (unsigned)off) {
#pragma unroll
      for (int j = 0; j < 10; ++j) red[threadIdx.x][j] += red[threadIdx.x + off][j];
    }
    __syncthreads();
  }
  if (threadIdx.x < 10) part[(b * 4 + s) * 10 + threadIdx.x] = red[0][threadIdx.x];
}

// ---------------- dense head: stage 2 (combine + dense2/3) ----------------
__global__ __launch_bounds__(64) void dense_final(
    const float* __restrict__ part,
    const float* __restrict__ B1,
    const float* __restrict__ W2, const float* __restrict__ B2,
    const float* __restrict__ W3, const float* __restrict__ B3,
    float* __restrict__ out) {
  const int b = blockIdx.x;
  __shared__ float y1[10], y2[10];
  if (threadIdx.x < 10) {
    int j = threadIdx.x;
    y1[j] = part[(b*4+0)*10 + j] + part[(b*4+1)*10 + j] +
            part[(b*4+2)*10 + j] + part[(b*4+3)*10 + j] + B1[j];
  }
  __syncthreads();
  if (threadIdx.x < 10) {
    int j = threadIdx.x;
    float s = B2[j];
#pragma unroll
    for (int i = 0; i < 10; ++i) s += y1[i] * W2[i * 10 + j];
    y2[j] = s;
  }
  __syncthreads();
  if (threadIdx.x < 10) {
    int j = threadIdx.x;
    float s = B3[j];
#pragma unroll
    for (int i = 0; i < 10; ++i) s += y2[i] * W3[i * 10 + j];
    out[b * 10 + j] = s;
  }
}

extern "C" void kernel_launch(void* const* d_in, const int* in_sizes, int n_in,
                              void* d_out, int out_size, void* d_ws, size_t ws_size,
                              hipStream_t stream) {
  const int*   inp = (const int*)d_in[0];
  const float* cw1 = (const float*)d_in[1];
  const float* cb1 = (const float*)d_in[2];
  const float* cw2 = (const float*)d_in[3];
  const float* cb2 = (const float*)d_in[4];
  const float* cw3 = (const float*)d_in[5];
  const float* cb3 = (const float*)d_in[6];
  const float* a1K = (const float*)d_in[7];
  const float* a1Q = (const float*)d_in[8];
  const float* a1V = (const float*)d_in[9];
  const float* a2K = (const float*)d_in[10];
  const float* a2Q = (const float*)d_in[11];
  const float* a2V = (const float*)d_in[12];
  const float* a3K = (const float*)d_in[13];
  const float* a3Q = (const float*)d_in[14];
  const float* a3V = (const float*)d_in[15];
  const float* dw1 = (const float*)d_in[16];
  const float* db1 = (const float*)d_in[17];
  const float* dw2 = (const float*)d_in[18];
  const float* db2 = (const float*)d_in[19];
  const float* dw3 = (const float*)d_in[20];
  const float* db3 = (const float*)d_in[21];
  float* outp = (float*)d_out;

  // workspace layout (floats); total 9,175,040 floats = 36.7 MB
  float* wsf  = (float*)d_ws;
  float* c1   = wsf;                 // [B,4,4096,5]  5,242,880 floats
  float* c2   = wsf + 5242880;       // [B,4,2048,5]  2,621,440 floats
  float* x    = wsf + 7864320;       // [B,S,20]      1,310,720 floats
  float* q    = wsf;                 // reuse c1 after conv2
  float* k    = wsf + 1310720;
  float* v    = wsf + 2621440;
  float* part = wsf + 3932160;       // [64,4,10] = 2,560 floats
  float* o    = c2;                  // reuse c2 after conv3

  conv1_kernel<<<1024, 256, 0, stream>>>(inp, cw1, cb1, c1);
  conv5_kernel<4096, false><<<512, 256, 0, stream>>>(c1, cw2, cb2, c2);
  conv5_kernel<2048, true><<<256, 256, 0, stream>>>(c2, cw3, cb3, x);

  proj_kernel<<<256, 256, 0, stream>>>(x, a1K, a1Q, a1V, q, k, v);
  attn_kernel<<<dim3(8, 64), 256, 0, stream>>>(q, k, v, o);

  proj_kernel<<<256, 256, 0, stream>>>(o, a2K, a2Q, a2V, q, k, v);
  attn_kernel<<<dim3(8, 64), 256, 0, stream>>>(q, k, v, x);

  proj_kernel<<<256, 256, 0, stream>>>(x, a3K, a3Q, a3V, q, k, v);
  attn_kernel<<<dim3(8, 64), 256, 0, stream>>>(q, k, v, o);

  dense1_partial<<<dim3(64, 4), 256, 0, stream>>>(o, dw1, part);
  dense_final<<<64, 64, 0, stream>>>(part, db1, dw2, db2, dw3, db3, outp);
}

// Round 6
// 285.797 us; speedup vs baseline: 2.1981x; 1.9423x over previous
//
#include <hip/hip_runtime.h>
#include <hip/hip_bf16.h>

// Model: one_hot -> 3x Conv2D(5,(4,4),(1,2),SAME) -> [B,S=1024,D=20]
//        -> 3x causal self-attention -> flatten -> 3x Dense(10)
// B=64, L=8192, S=1024, D=20.
// Attention uses bf16 MFMA (16x16x32): D=20 padded to K=32, scores |s|<<1 so
// streaming softmax needs no max-subtraction and no rescale (exact fp32 C-frag
// accumulation). All other stages fp32.

#define B_ 64
#define L_ 8192
#define S_ 1024
#define D_ 20

typedef unsigned short ushort_t;
typedef __attribute__((ext_vector_type(8))) short short8_t;  // 8 bf16 (4 VGPRs)
typedef __attribute__((ext_vector_type(4))) float f32x4_t;   // MFMA C/D

__device__ __forceinline__ ushort_t f2bf(float f) {          // RNE fp32->bf16
  unsigned u = __float_as_uint(f);
  return (ushort_t)((u + 0x7fffu + ((u >> 16) & 1u)) >> 16);
}
__device__ __forceinline__ float bf2f(ushort_t h) {
  return __uint_as_float(((unsigned)h) << 16);
}

// ---------------- conv1: one-hot input, CI=1 ----------------
__global__ __launch_bounds__(256) void conv1_kernel(
    const int* __restrict__ inp, const float* __restrict__ W,
    const float* __restrict__ Bi, float* __restrict__ out) {
  __shared__ float ws[80];
  __shared__ float bs[5];
  if (threadIdx.x < 80) ws[threadIdx.x] = W[threadIdx.x];
  if (threadIdx.x < 5)  bs[threadIdx.x] = Bi[threadIdx.x];
  __syncthreads();
  int idx = blockIdx.x * 256 + threadIdx.x;   // (b, wo), wo in [0,4096)
  int b  = idx >> 12;
  int wo = idx & 4095;
  float acc[4][5];
#pragma unroll
  for (int h = 0; h < 4; ++h)
#pragma unroll
    for (int c = 0; c < 5; ++c) acc[h][c] = bs[c];
  const int* ib = inp + (size_t)b * L_;
#pragma unroll
  for (int kw = 0; kw < 4; ++kw) {
    int wi = 2 * wo - 1 + kw;
    if (wi >= 0 && wi < L_) {
      int v = ib[wi];
#pragma unroll
      for (int h = 0; h < 4; ++h) {
        int kh = v - h + 1;
        if (kh >= 0 && kh < 4) {
#pragma unroll
          for (int c = 0; c < 5; ++c) acc[h][c] += ws[(kh * 4 + kw) * 5 + c];
        }
      }
    }
  }
  float* ob = out + (size_t)b * 4 * 4096 * 5;
#pragma unroll
  for (int h = 0; h < 4; ++h)
#pragma unroll
    for (int c = 0; c < 5; ++c) ob[(h * 4096 + wo) * 5 + c] = acc[h][c];
}

// ---------------- conv2/conv3: CI=5, CO=5 (R2-proven version) ----------------
template <int WIN, bool TRANS>
__global__ __launch_bounds__(256) void conv5_kernel(
    const float* __restrict__ in, const float* __restrict__ W,
    const float* __restrict__ Bi, float* __restrict__ out) {
  constexpr int WOUT = WIN / 2;
  __shared__ float ws[400];
  __shared__ float bs[5];
  for (int j = threadIdx.x; j < 400; j += 256) ws[j] = W[j];
  if (threadIdx.x < 5) bs[threadIdx.x] = Bi[threadIdx.x];
  __syncthreads();
  int idx = blockIdx.x * 256 + threadIdx.x;   // (b, wo)
  int b  = idx / WOUT;
  int wo = idx % WOUT;
  float val[4][4][5];
#pragma unroll
  for (int hi = 0; hi < 4; ++hi) {
    const float* ir = in + ((size_t)b * 4 + hi) * WIN * 5;
#pragma unroll
    for (int kw = 0; kw < 4; ++kw) {
      int wi = 2 * wo - 1 + kw;
      bool ok = (wi >= 0 && wi < WIN);
#pragma unroll
      for (int ci = 0; ci < 5; ++ci) val[hi][kw][ci] = ok ? ir[wi * 5 + ci] : 0.f;
    }
  }
  float acc[4][5];
#pragma unroll
  for (int h = 0; h < 4; ++h)
#pragma unroll
    for (int c = 0; c < 5; ++c) acc[h][c] = bs[c];
#pragma unroll
  for (int kh = 0; kh < 4; ++kh)
#pragma unroll
    for (int kw = 0; kw < 4; ++kw)
#pragma unroll
      for (int ci = 0; ci < 5; ++ci) {
        const float* wp = ws + ((kh * 4 + kw) * 5 + ci) * 5;
        float w0 = wp[0], w1 = wp[1], w2 = wp[2], w3 = wp[3], w4 = wp[4];
#pragma unroll
        for (int h = 0; h < 4; ++h) {
          int hi = h - 1 + kh;
          if (hi >= 0 && hi < 4) {
            float x = val[hi][kw][ci];
            acc[h][0] += w0 * x; acc[h][1] += w1 * x; acc[h][2] += w2 * x;
            acc[h][3] += w3 * x; acc[h][4] += w4 * x;
          }
        }
      }
  if (TRANS) {
    float* ob = out + ((size_t)b * WOUT + wo) * 20;
#pragma unroll
    for (int h = 0; h < 4; ++h)
#pragma unroll
      for (int c = 0; c < 5; ++c) ob[h * 5 + c] = acc[h][c];
  } else {
    float* ob = out + (size_t)b * 4 * WOUT * 5;
#pragma unroll
    for (int h = 0; h < 4; ++h)
#pragma unroll
      for (int c = 0; c < 5; ++c) ob[(h * WOUT + wo) * 5 + c] = acc[h][c];
  }
}

// ---------------- Q/K/V projection -> bf16 MFMA layouts ----------------
// Qb/Kb: [b][s][32] bf16, d 20..31 ZERO (K-dim padding must be zero).
// Vt:    [b][32][1024] bf16, d-major (rows 20..31 never read -> not written).
// Q folded scale 1/sqrt(20).
__global__ __launch_bounds__(256) void proj_kernel(
    const float* __restrict__ X,
    const float* __restrict__ Kw, const float* __restrict__ Qw,
    const float* __restrict__ Vw,
    ushort_t* __restrict__ Qb, ushort_t* __restrict__ Kb,
    ushort_t* __restrict__ Vt) {
  __shared__ float kw[400], qw[400], vw[400];
  for (int j = threadIdx.x; j < 400; j += 256) {
    kw[j] = Kw[j]; qw[j] = Qw[j]; vw[j] = Vw[j];
  }
  __syncthreads();
  int r = blockIdx.x * 256 + threadIdx.x;   // row in [0, 65536)
  const float4* xr4 = (const float4*)(X + (size_t)r * D_);
  float x[D_];
#pragma unroll
  for (int i = 0; i < 5; ++i) {
    float4 t = xr4[i];
    x[4*i] = t.x; x[4*i+1] = t.y; x[4*i+2] = t.z; x[4*i+3] = t.w;
  }
  float q[D_], k[D_], v[D_];
#pragma unroll
  for (int j = 0; j < D_; ++j) { q[j] = 0.f; k[j] = 0.f; v[j] = 0.f; }
#pragma unroll
  for (int i = 0; i < D_; ++i) {
#pragma unroll
    for (int j = 0; j < D_; ++j) {
      q[j] += x[i] * qw[i * D_ + j];
      k[j] += x[i] * kw[i * D_ + j];
      v[j] += x[i] * vw[i * D_ + j];
    }
  }
  const float sc = 0.22360679774997896f;  // 1/sqrt(20)
  ushort_t qt[32], kt[32];
#pragma unroll
  for (int j = 0; j < D_; ++j) { qt[j] = f2bf(q[j] * sc); kt[j] = f2bf(k[j]); }
#pragma unroll
  for (int j = D_; j < 32; ++j) { qt[j] = 0; kt[j] = 0; }
  int4* qd = (int4*)(Qb + (size_t)r * 32);
  int4* kd = (int4*)(Kb + (size_t)r * 32);
#pragma unroll
  for (int j = 0; j < 4; ++j) {
    qd[j] = *(const int4*)(qt + 8 * j);
    kd[j] = *(const int4*)(kt + 8 * j);
  }
  const int bb = r >> 10, ss = r & 1023;
  ushort_t* vbase = Vt + ((size_t)bb * 32) * 1024 + ss;
#pragma unroll
  for (int d = 0; d < D_; ++d) vbase[d * 1024] = f2bf(v[d]);  // coalesced across lanes
}

// ---------------- causal attention via bf16 MFMA ----------------
// Grid (16,64): strip = 15-bx (LPT), 64 q-rows/block, wave w owns rows
// qbase=q0+16w..+15 (A-frag: row=lane&15, k=quad*8+j — m120-verified layout).
// Per 128-t staged tile: 4 chunks of 32 t. Chunk: 2 QK MFMAs (t-halves),
// exp+mask on C-frags (row=quad*4+reg, col=lane&15), P->LDS->A-frag
// round-trip (wave-synchronous, lgkmcnt fence), 2 PV MFMAs (d 0..15, 16..31;
// cols>=20 discarded). l accumulated from bf16-rounded P so normalization
// cancels rounding. No max-subtraction needed (|s|<<1). O in fp32 C-frags.
#define TT_ 128
__global__ __launch_bounds__(256) void attn_kernel(
    const ushort_t* __restrict__ Qb, const ushort_t* __restrict__ Kb,
    const ushort_t* __restrict__ Vt, float* __restrict__ out) {
  const int b     = blockIdx.y;
  const int strip = 15 - blockIdx.x;      // heavy strips first
  const int q0    = strip * 64;
  const int tid   = threadIdx.x;
  const int w     = tid >> 6;             // wave 0..3
  const int lane  = tid & 63;
  const int n     = lane & 15;
  const int quad  = lane >> 4;
  const int qbase = q0 + 16 * w;
  __shared__ ushort_t kts[128 * 40];      // K tile, row stride 40 us (80 B)
  __shared__ ushort_t vts[32 * 136];      // V^T tile, row stride 136 us (272 B)
  __shared__ ushort_t pts[4][16 * 40];    // per-wave P scratch, stride 40 us
  const ushort_t* KbB = Kb + (size_t)b * 1024 * 32;
  const ushort_t* VtB = Vt + (size_t)b * 32 * 1024;
  // Q A-frag from global: row qbase+n, k-chunk quad*8..+8
  short8_t qfrag = *(const short8_t*)(Qb + ((size_t)(b * 1024 + qbase + n)) * 32 + quad * 8);
  f32x4_t oA = {0.f, 0.f, 0.f, 0.f};
  f32x4_t oB = {0.f, 0.f, 0.f, 0.f};
  f32x4_t lac = {0.f, 0.f, 0.f, 0.f};
  const f32x4_t zero = {0.f, 0.f, 0.f, 0.f};
  const int Tw = qbase + 16;              // exclusive t bound for this wave
  const int nt = q0 + 64;                 // block-uniform staging bound
  ushort_t* prow = pts[w];
  for (int t0 = 0; t0 < nt; t0 += TT_) {
    __syncthreads();
    // stage K rows [t0, t0+128): 512 x 16B jobs
    for (int i = tid; i < 512; i += 256) {
      int row = i >> 2, qc = i & 3;
      *(int4*)(kts + row * 40 + qc * 8) =
          *(const int4*)(KbB + (size_t)(t0 + row) * 32 + qc * 8);
    }
    // stage V^T rows 0..19, cols [t0, t0+128): 320 x 16B jobs
    for (int i = tid; i < 320; i += 256) {
      int row = i >> 4, cc = i & 15;
      *(int4*)(vts + row * 136 + cc * 8) =
          *(const int4*)(VtB + (size_t)row * 1024 + t0 + cc * 8);
    }
    __syncthreads();
#pragma unroll 1
    for (int cc = 0; cc < 4; ++cc) {
      const int tc = t0 + cc * 32;
      if (tc >= Tw) break;                // wave-uniform
      const short8_t kfA = *(const short8_t*)(kts + (cc * 32 + n) * 40 + quad * 8);
      const short8_t kfB = *(const short8_t*)(kts + (cc * 32 + 16 + n) * 40 + quad * 8);
      f32x4_t sA = __builtin_amdgcn_mfma_f32_16x16x32_bf16(qfrag, kfA, zero, 0, 0, 0);
      f32x4_t sB = __builtin_amdgcn_mfma_f32_16x16x32_bf16(qfrag, kfB, zero, 0, 0, 0);
#pragma unroll
      for (int r = 0; r < 4; ++r) {
        const int qg = qbase + quad * 4 + r;
        float pA = (tc + n      <= qg) ? __expf(sA[r]) : 0.f;
        float pB = (tc + 16 + n <= qg) ? __expf(sB[r]) : 0.f;
        ushort_t hA = f2bf(pA), hB = f2bf(pB);
        lac[r] += bf2f(hA) + bf2f(hB);    // consistent with bf16 P used in PV
        prow[(quad * 4 + r) * 40 + n]      = hA;
        prow[(quad * 4 + r) * 40 + 16 + n] = hB;
      }
      __asm__ volatile("s_waitcnt lgkmcnt(0)" ::: "memory");  // wave-sync LDS RAW
      short8_t pfrag = *(const short8_t*)(prow + n * 40 + quad * 8);
      const short8_t vfA = *(const short8_t*)(vts + n * 136 + cc * 32 + quad * 8);
      const short8_t vfB = *(const short8_t*)(vts + (16 + n) * 136 + cc * 32 + quad * 8);
      oA = __builtin_amdgcn_mfma_f32_16x16x32_bf16(pfrag, vfA, oA, 0, 0, 0);
      oB = __builtin_amdgcn_mfma_f32_16x16x32_bf16(pfrag, vfB, oB, 0, 0, 0);
    }
  }
  // reduce l over the 16 col-lanes of each quad
#pragma unroll
  for (int m = 1; m <= 8; m <<= 1) {
#pragma unroll
    for (int r = 0; r < 4; ++r) lac[r] += __shfl_xor(lac[r], m, 64);
  }
  float* ob = out + ((size_t)(b * 1024 + qbase)) * 20;
#pragma unroll
  for (int r = 0; r < 4; ++r) {
    const float inv = 1.f / lac[r];
    const int qq = quad * 4 + r;
    ob[qq * 20 + n] = oA[r] * inv;                    // d = 0..15
    if (n < 4) ob[qq * 20 + 16 + n] = oB[r] * inv;    // d = 16..19
  }
}

// ---------------- dense head: stage 1 (partials) ----------------
__global__ __launch_bounds__(256) void dense1_partial(
    const float* __restrict__ X,   // [64, 20480]
    const float* __restrict__ W1,  // [20480, 10]
    float* __restrict__ part) {    // [64, 4, 10]
  const int b = blockIdx.x;
  const int s = blockIdx.y;
  const float* xb = X + (size_t)b * 20480 + s * 5120;
  const float* wb = W1 + (size_t)s * 5120 * 10;
  float acc[10];
#pragma unroll
  for (int j = 0; j < 10; ++j) acc[j] = 0.f;
  for (int i = threadIdx.x; i < 5120; i += 256) {
    float v = xb[i];
    const float* wr = wb + i * 10;
#pragma unroll
    for (int j = 0; j < 10; ++j) acc[j] += v * wr[j];
  }
  __shared__ float red[256][10];
#pragma unroll
  for (int j = 0; j < 10; ++j) red[threadIdx.x][j] = acc[j];
  __syncthreads();
  for (int off = 128; off > 0; off >>= 1) {
    if (threadIdx.x < (unsigned)off) {
#pragma unroll
      for (int j = 0; j < 10; ++j) red[threadIdx.x][j] += red[threadIdx.x + off][j];
    }
    __syncthreads();
  }
  if (threadIdx.x < 10) part[(b * 4 + s) * 10 + threadIdx.x] = red[0][threadIdx.x];
}

// ---------------- dense head: stage 2 (combine + dense2/3) ----------------
__global__ __launch_bounds__(64) void dense_final(
    const float* __restrict__ part,
    const float* __restrict__ B1,
    const float* __restrict__ W2, const float* __restrict__ B2,
    const float* __restrict__ W3, const float* __restrict__ B3,
    float* __restrict__ out) {
  const int b = blockIdx.x;
  __shared__ float y1[10], y2[10];
  if (threadIdx.x < 10) {
    int j = threadIdx.x;
    y1[j] = part[(b*4+0)*10 + j] + part[(b*4+1)*10 + j] +
            part[(b*4+2)*10 + j] + part[(b*4+3)*10 + j] + B1[j];
  }
  __syncthreads();
  if (threadIdx.x < 10) {
    int j = threadIdx.x;
    float s = B2[j];
#pragma unroll
    for (int i = 0; i < 10; ++i) s += y1[i] * W2[i * 10 + j];
    y2[j] = s;
  }
  __syncthreads();
  if (threadIdx.x < 10) {
    int j = threadIdx.x;
    float s = B3[j];
#pragma unroll
    for (int i = 0; i < 10; ++i) s += y2[i] * W3[i * 10 + j];
    out[b * 10 + j] = s;
  }
}

extern "C" void kernel_launch(void* const* d_in, const int* in_sizes, int n_in,
                              void* d_out, int out_size, void* d_ws, size_t ws_size,
                              hipStream_t stream) {
  const int*   inp = (const int*)d_in[0];
  const float* cw1 = (const float*)d_in[1];
  const float* cb1 = (const float*)d_in[2];
  const float* cw2 = (const float*)d_in[3];
  const float* cb2 = (const float*)d_in[4];
  const float* cw3 = (const float*)d_in[5];
  const float* cb3 = (const float*)d_in[6];
  const float* a1K = (const float*)d_in[7];
  const float* a1Q = (const float*)d_in[8];
  const float* a1V = (const float*)d_in[9];
  const float* a2K = (const float*)d_in[10];
  const float* a2Q = (const float*)d_in[11];
  const float* a2V = (const float*)d_in[12];
  const float* a3K = (const float*)d_in[13];
  const float* a3Q = (const float*)d_in[14];
  const float* a3V = (const float*)d_in[15];
  const float* dw1 = (const float*)d_in[16];
  const float* db1 = (const float*)d_in[17];
  const float* dw2 = (const float*)d_in[18];
  const float* db2 = (const float*)d_in[19];
  const float* dw3 = (const float*)d_in[20];
  const float* db3 = (const float*)d_in[21];
  float* outp = (float*)d_out;

  // workspace layout (float units, 9,175,040 floats = 36.7 MB as before)
  float* wsf = (float*)d_ws;
  float*    c1   = wsf;                         // [B,4,4096,5]   [0 .. 5,242,880)
  float*    c2   = wsf + 5242880;               // [B,4,2048,5]   [5,242,880 .. 7,864,320)
  float*    x    = wsf + 7864320;               // [B,S,20]       [7,864,320 .. 9,175,040)
  ushort_t* qb   = (ushort_t*)(wsf);            // [B,S,32] bf16  [0 .. 1,048,576) fl
  ushort_t* kb   = (ushort_t*)(wsf + 1048576);  //                [1,048,576 .. 2,097,152)
  ushort_t* vt   = (ushort_t*)(wsf + 2097152);  // [B,32,S] bf16  [2,097,152 .. 3,145,728)
  float*    o    = wsf + 3145728;               // [B,S,20]       [3,145,728 .. 4,456,448)
  float*    part = wsf + 4456448;               // [64,4,10]

  conv1_kernel<<<1024, 256, 0, stream>>>(inp, cw1, cb1, c1);
  conv5_kernel<4096, false><<<512, 256, 0, stream>>>(c1, cw2, cb2, c2);
  conv5_kernel<2048, true><<<256, 256, 0, stream>>>(c2, cw3, cb3, x);
  // c1 dead from here; qb/kb/vt/o live in its footprint.

  proj_kernel<<<256, 256, 0, stream>>>(x, a1K, a1Q, a1V, qb, kb, vt);
  attn_kernel<<<dim3(16, 64), 256, 0, stream>>>(qb, kb, vt, o);

  proj_kernel<<<256, 256, 0, stream>>>(o, a2K, a2Q, a2V, qb, kb, vt);
  attn_kernel<<<dim3(16, 64), 256, 0, stream>>>(qb, kb, vt, x);

  proj_kernel<<<256, 256, 0, stream>>>(x, a3K, a3Q, a3V, qb, kb, vt);
  attn_kernel<<<dim3(16, 64), 256, 0, stream>>>(qb, kb, vt, o);

  dense1_partial<<<dim3(64, 4), 256, 0, stream>>>(o, dw1, part);
  dense_final<<<64, 64, 0, stream>>>(part, db1, dw2, db2, dw3, db3, outp);
}

// Round 7
// 264.553 us; speedup vs baseline: 2.3746x; 1.0803x over previous
//
#include <hip/hip_runtime.h>
#include <hip/hip_bf16.h>

// Model: one_hot -> 3x Conv2D(5,(4,4),(1,2),SAME) -> [B,S=1024,D=20]
//        -> 3x causal self-attention -> flatten -> 3x Dense(10)
// B=64, L=8192, S=1024, D=20.
// Attention uses bf16 MFMA (16x16x32): D=20 padded to K=32, scores |s|<<1 so
// streaming softmax needs no max-subtraction and no rescale (exact fp32 C-frag
// accumulation). All other stages fp32.

#define B_ 64
#define L_ 8192
#define S_ 1024
#define D_ 20

typedef unsigned short ushort_t;
typedef __attribute__((ext_vector_type(8))) short short8_t;  // 8 bf16 (4 VGPRs)
typedef __attribute__((ext_vector_type(4))) float f32x4_t;   // MFMA C/D

__device__ __forceinline__ ushort_t f2bf(float f) {          // RNE fp32->bf16
  unsigned u = __float_as_uint(f);
  return (ushort_t)((u + 0x7fffu + ((u >> 16) & 1u)) >> 16);
}
__device__ __forceinline__ float bf2f(ushort_t h) {
  return __uint_as_float(((unsigned)h) << 16);
}

// ---------------- conv1: one-hot input, CI=1 ----------------
__global__ __launch_bounds__(256) void conv1_kernel(
    const int* __restrict__ inp, const float* __restrict__ W,
    const float* __restrict__ Bi, float* __restrict__ out) {
  __shared__ float ws[80];
  __shared__ float bs[5];
  if (threadIdx.x < 80) ws[threadIdx.x] = W[threadIdx.x];
  if (threadIdx.x < 5)  bs[threadIdx.x] = Bi[threadIdx.x];
  __syncthreads();
  int idx = blockIdx.x * 256 + threadIdx.x;   // (b, wo), wo in [0,4096)
  int b  = idx >> 12;
  int wo = idx & 4095;
  float acc[4][5];
#pragma unroll
  for (int h = 0; h < 4; ++h)
#pragma unroll
    for (int c = 0; c < 5; ++c) acc[h][c] = bs[c];
  const int* ib = inp + (size_t)b * L_;
#pragma unroll
  for (int kw = 0; kw < 4; ++kw) {
    int wi = 2 * wo - 1 + kw;
    if (wi >= 0 && wi < L_) {
      int v = ib[wi];
#pragma unroll
      for (int h = 0; h < 4; ++h) {
        int kh = v - h + 1;
        if (kh >= 0 && kh < 4) {
#pragma unroll
          for (int c = 0; c < 5; ++c) acc[h][c] += ws[(kh * 4 + kw) * 5 + c];
        }
      }
    }
  }
  float* ob = out + (size_t)b * 4 * 4096 * 5;
#pragma unroll
  for (int h = 0; h < 4; ++h)
#pragma unroll
    for (int c = 0; c < 5; ++c) ob[(h * 4096 + wo) * 5 + c] = acc[h][c];
}

// ---------------- conv2/conv3: CI=5, CO=5 (R2-proven version) ----------------
template <int WIN, bool TRANS>
__global__ __launch_bounds__(256) void conv5_kernel(
    const float* __restrict__ in, const float* __restrict__ W,
    const float* __restrict__ Bi, float* __restrict__ out) {
  constexpr int WOUT = WIN / 2;
  __shared__ float ws[400];
  __shared__ float bs[5];
  for (int j = threadIdx.x; j < 400; j += 256) ws[j] = W[j];
  if (threadIdx.x < 5) bs[threadIdx.x] = Bi[threadIdx.x];
  __syncthreads();
  int idx = blockIdx.x * 256 + threadIdx.x;   // (b, wo)
  int b  = idx / WOUT;
  int wo = idx % WOUT;
  float val[4][4][5];
#pragma unroll
  for (int hi = 0; hi < 4; ++hi) {
    const float* ir = in + ((size_t)b * 4 + hi) * WIN * 5;
#pragma unroll
    for (int kw = 0; kw < 4; ++kw) {
      int wi = 2 * wo - 1 + kw;
      bool ok = (wi >= 0 && wi < WIN);
#pragma unroll
      for (int ci = 0; ci < 5; ++ci) val[hi][kw][ci] = ok ? ir[wi * 5 + ci] : 0.f;
    }
  }
  float acc[4][5];
#pragma unroll
  for (int h = 0; h < 4; ++h)
#pragma unroll
    for (int c = 0; c < 5; ++c) acc[h][c] = bs[c];
#pragma unroll
  for (int kh = 0; kh < 4; ++kh)
#pragma unroll
    for (int kw = 0; kw < 4; ++kw)
#pragma unroll
      for (int ci = 0; ci < 5; ++ci) {
        const float* wp = ws + ((kh * 4 + kw) * 5 + ci) * 5;
        float w0 = wp[0], w1 = wp[1], w2 = wp[2], w3 = wp[3], w4 = wp[4];
#pragma unroll
        for (int h = 0; h < 4; ++h) {
          int hi = h - 1 + kh;
          if (hi >= 0 && hi < 4) {
            float x = val[hi][kw][ci];
            acc[h][0] += w0 * x; acc[h][1] += w1 * x; acc[h][2] += w2 * x;
            acc[h][3] += w3 * x; acc[h][4] += w4 * x;
          }
        }
      }
  if (TRANS) {
    float* ob = out + ((size_t)b * WOUT + wo) * 20;
#pragma unroll
    for (int h = 0; h < 4; ++h)
#pragma unroll
      for (int c = 0; c < 5; ++c) ob[h * 5 + c] = acc[h][c];
  } else {
    float* ob = out + (size_t)b * 4 * WOUT * 5;
#pragma unroll
    for (int h = 0; h < 4; ++h)
#pragma unroll
      for (int c = 0; c < 5; ++c) ob[(h * WOUT + wo) * 5 + c] = acc[h][c];
  }
}

// ---------------- Q/K/V projection -> bf16 MFMA layouts ----------------
// Qb/Kb: [b][s][32] bf16, d 20..31 ZERO (K-dim padding must be zero).
// Vt:    [b][32][1024] bf16, d-major (rows 20..31 never read -> not written).
// Q folded scale 1/sqrt(20).
__global__ __launch_bounds__(256) void proj_kernel(
    const float* __restrict__ X,
    const float* __restrict__ Kw, const float* __restrict__ Qw,
    const float* __restrict__ Vw,
    ushort_t* __restrict__ Qb, ushort_t* __restrict__ Kb,
    ushort_t* __restrict__ Vt) {
  __shared__ float kw[400], qw[400], vw[400];
  for (int j = threadIdx.x; j < 400; j += 256) {
    kw[j] = Kw[j]; qw[j] = Qw[j]; vw[j] = Vw[j];
  }
  __syncthreads();
  int r = blockIdx.x * 256 + threadIdx.x;   // row in [0, 65536)
  const float4* xr4 = (const float4*)(X + (size_t)r * D_);
  float x[D_];
#pragma unroll
  for (int i = 0; i < 5; ++i) {
    float4 t = xr4[i];
    x[4*i] = t.x; x[4*i+1] = t.y; x[4*i+2] = t.z; x[4*i+3] = t.w;
  }
  float q[D_], k[D_], v[D_];
#pragma unroll
  for (int j = 0; j < D_; ++j) { q[j] = 0.f; k[j] = 0.f; v[j] = 0.f; }
#pragma unroll
  for (int i = 0; i < D_; ++i) {
#pragma unroll
    for (int j = 0; j < D_; ++j) {
      q[j] += x[i] * qw[i * D_ + j];
      k[j] += x[i] * kw[i * D_ + j];
      v[j] += x[i] * vw[i * D_ + j];
    }
  }
  const float sc = 0.22360679774997896f;  // 1/sqrt(20)
  ushort_t qt[32], kt[32];
#pragma unroll
  for (int j = 0; j < D_; ++j) { qt[j] = f2bf(q[j] * sc); kt[j] = f2bf(k[j]); }
#pragma unroll
  for (int j = D_; j < 32; ++j) { qt[j] = 0; kt[j] = 0; }
  int4* qd = (int4*)(Qb + (size_t)r * 32);
  int4* kd = (int4*)(Kb + (size_t)r * 32);
#pragma unroll
  for (int j = 0; j < 4; ++j) {
    qd[j] = *(const int4*)(qt + 8 * j);
    kd[j] = *(const int4*)(kt + 8 * j);
  }
  const int bb = r >> 10, ss = r & 1023;
  ushort_t* vbase = Vt + ((size_t)bb * 32) * 1024 + ss;
#pragma unroll
  for (int d = 0; d < D_; ++d) vbase[d * 1024] = f2bf(v[d]);  // coalesced across lanes
}

// ---------------- causal attention via bf16 MFMA ----------------
// 16 strips of 64 q-rows per batch. Strip swizzle: co-resident blocks are
// stride-256 apart (= bx equal, by differing by 16), so
// strip = (bx + 4*(by>>4)) & 15 gives each CU strips {c,c+4,c+8,c+12}
// (CU load 28..40 tile-units vs 4..64 unswizzled -> makespan 1.18x not 1.9x).
// Wave w owns rows qbase=q0+16w..+15 (A-frag: row=lane&15, k=quad*8+j).
// Per 128-t staged tile: 4 chunks of 32 t. Chunk: 2 QK MFMAs (t-halves),
// exp+mask on C-frags (row=quad*4+reg, col=lane&15), P->LDS->A-frag
// round-trip (wave-synchronous, lgkmcnt fence), 2 PV MFMAs (d 0..15, 16..31;
// cols>=20 discarded). l accumulated from bf16-rounded P so normalization
// cancels rounding. No max-subtraction needed (|s|<<1). O in fp32 C-frags.
#define TT_ 128
__global__ __launch_bounds__(256) void attn_kernel(
    const ushort_t* __restrict__ Qb, const ushort_t* __restrict__ Kb,
    const ushort_t* __restrict__ Vt, float* __restrict__ out) {
  const int b     = blockIdx.y;
  const int strip = (blockIdx.x + 4 * (blockIdx.y >> 4)) & 15;
  const int q0    = strip * 64;
  const int tid   = threadIdx.x;
  const int w     = tid >> 6;             // wave 0..3
  const int lane  = tid & 63;
  const int n     = lane & 15;
  const int quad  = lane >> 4;
  const int qbase = q0 + 16 * w;
  __shared__ ushort_t kts[128 * 40];      // K tile, row stride 40 us (80 B)
  __shared__ ushort_t vts[32 * 136];      // V^T tile, row stride 136 us (272 B)
  __shared__ ushort_t pts[4][16 * 40];    // per-wave P scratch, stride 40 us
  const ushort_t* KbB = Kb + (size_t)b * 1024 * 32;
  const ushort_t* VtB = Vt + (size_t)b * 32 * 1024;
  // Q A-frag from global: row qbase+n, k-chunk quad*8..+8
  short8_t qfrag = *(const short8_t*)(Qb + ((size_t)(b * 1024 + qbase + n)) * 32 + quad * 8);
  f32x4_t oA = {0.f, 0.f, 0.f, 0.f};
  f32x4_t oB = {0.f, 0.f, 0.f, 0.f};
  f32x4_t lac = {0.f, 0.f, 0.f, 0.f};
  const f32x4_t zero = {0.f, 0.f, 0.f, 0.f};
  const int Tw = qbase + 16;              // exclusive t bound for this wave
  const int nt = q0 + 64;                 // block-uniform staging bound
  ushort_t* prow = pts[w];
  for (int t0 = 0; t0 < nt; t0 += TT_) {
    __syncthreads();
    // stage K rows [t0, t0+128): 512 x 16B jobs
    for (int i = tid; i < 512; i += 256) {
      int row = i >> 2, qc = i & 3;
      *(int4*)(kts + row * 40 + qc * 8) =
          *(const int4*)(KbB + (size_t)(t0 + row) * 32 + qc * 8);
    }
    // stage V^T rows 0..19, cols [t0, t0+128): 320 x 16B jobs
    for (int i = tid; i < 320; i += 256) {
      int row = i >> 4, cc = i & 15;
      *(int4*)(vts + row * 136 + cc * 8) =
          *(const int4*)(VtB + (size_t)row * 1024 + t0 + cc * 8);
    }
    __syncthreads();
#pragma unroll 1
    for (int cc = 0; cc < 4; ++cc) {
      const int tc = t0 + cc * 32;
      if (tc >= Tw) break;                // wave-uniform
      const short8_t kfA = *(const short8_t*)(kts + (cc * 32 + n) * 40 + quad * 8);
      const short8_t kfB = *(const short8_t*)(kts + (cc * 32 + 16 + n) * 40 + quad * 8);
      f32x4_t sA = __builtin_amdgcn_mfma_f32_16x16x32_bf16(qfrag, kfA, zero, 0, 0, 0);
      f32x4_t sB = __builtin_amdgcn_mfma_f32_16x16x32_bf16(qfrag, kfB, zero, 0, 0, 0);
#pragma unroll
      for (int r = 0; r < 4; ++r) {
        const int qg = qbase + quad * 4 + r;
        float pA = (tc + n      <= qg) ? __expf(sA[r]) : 0.f;
        float pB = (tc + 16 + n <= qg) ? __expf(sB[r]) : 0.f;
        ushort_t hA = f2bf(pA), hB = f2bf(pB);
        lac[r] += bf2f(hA) + bf2f(hB);    // consistent with bf16 P used in PV
        prow[(quad * 4 + r) * 40 + n]      = hA;
        prow[(quad * 4 + r) * 40 + 16 + n] = hB;
      }
      __asm__ volatile("s_waitcnt lgkmcnt(0)" ::: "memory");  // wave-sync LDS RAW
      short8_t pfrag = *(const short8_t*)(prow + n * 40 + quad * 8);
      const short8_t vfA = *(const short8_t*)(vts + n * 136 + cc * 32 + quad * 8);
      const short8_t vfB = *(const short8_t*)(vts + (16 + n) * 136 + cc * 32 + quad * 8);
      oA = __builtin_amdgcn_mfma_f32_16x16x32_bf16(pfrag, vfA, oA, 0, 0, 0);
      oB = __builtin_amdgcn_mfma_f32_16x16x32_bf16(pfrag, vfB, oB, 0, 0, 0);
    }
  }
  // reduce l over the 16 col-lanes of each quad
#pragma unroll
  for (int m = 1; m <= 8; m <<= 1) {
#pragma unroll
    for (int r = 0; r < 4; ++r) lac[r] += __shfl_xor(lac[r], m, 64);
  }
  float* ob = out + ((size_t)(b * 1024 + qbase)) * 20;
#pragma unroll
  for (int r = 0; r < 4; ++r) {
    const float inv = 1.f / lac[r];
    const int qq = quad * 4 + r;
    ob[qq * 20 + n] = oA[r] * inv;                    // d = 0..15
    if (n < 4) ob[qq * 20 + 16 + n] = oB[r] * inv;    // d = 16..19
  }
}

// ---------------- W1 transpose (once per call; makes dense1 streams contiguous)
__global__ __launch_bounds__(256) void transpose_w1(
    const float* __restrict__ W1,   // [20480, 10]
    float* __restrict__ W1T) {      // [10, 20480]
  int idx = blockIdx.x * 256 + threadIdx.x;        // 204800 total
  int j = idx / 20480;
  int i = idx % 20480;                              // lane-consecutive i -> coalesced write
  W1T[idx] = W1[i * 10 + j];
}

// ---------------- dense head: stage 1 (partials, vectorized) ----------------
__global__ __launch_bounds__(256) void dense1_partial(
    const float* __restrict__ X,    // [64, 20480]
    const float* __restrict__ W1T,  // [10, 20480]
    float* __restrict__ part) {     // [64, 4, 10]
  const int b = blockIdx.x;
  const int s = blockIdx.y;
  const float4* xb = (const float4*)(X + (size_t)b * 20480 + s * 5120);
  float acc[10];
#pragma unroll
  for (int j = 0; j < 10; ++j) acc[j] = 0.f;
  for (int i = threadIdx.x; i < 1280; i += 256) {   // float4 index within 5120
    float4 xv = xb[i];
#pragma unroll
    for (int j = 0; j < 10; ++j) {
      float4 wv = ((const float4*)(W1T + (size_t)j * 20480 + s * 5120))[i];
      acc[j] += xv.x * wv.x + xv.y * wv.y + xv.z * wv.z + xv.w * wv.w;
    }
  }
  __shared__ float red[256][10];
#pragma unroll
  for (int j = 0; j < 10; ++j) red[threadIdx.x][j] = acc[j];
  __syncthreads();
  for (int off = 128; off > 0; off >>= 1) {
    if (threadIdx.x < (unsigned)off) {
#pragma unroll
      for (int j = 0; j < 10; ++j) red[threadIdx.x][j] += red[threadIdx.x + off][j];
    }
    __syncthreads();
  }
  if (threadIdx.x < 10) part[(b * 4 + s) * 10 + threadIdx.x] = red[0][threadIdx.x];
}

// ---------------- dense head: stage 2 (combine + dense2/3) ----------------
__global__ __launch_bounds__(64) void dense_final(
    const float* __restrict__ part,
    const float* __restrict__ B1,
    const float* __restrict__ W2, const float* __restrict__ B2,
    const float* __restrict__ W3, const float* __restrict__ B3,
    float* __restrict__ out) {
  const int b = blockIdx.x;
  __shared__ float y1[10], y2[10];
  if (threadIdx.x < 10) {
    int j = threadIdx.x;
    y1[j] = part[(b*4+0)*10 + j] + part[(b*4+1)*10 + j] +
            part[(b*4+2)*10 + j] + part[(b*4+3)*10 + j] + B1[j];
  }
  __syncthreads();
  if (threadIdx.x < 10) {
    int j = threadIdx.x;
    float s = B2[j];
#pragma unroll
    for (int i = 0; i < 10; ++i) s += y1[i] * W2[i * 10 + j];
    y2[j] = s;
  }
  __syncthreads();
  if (threadIdx.x < 10) {
    int j = threadIdx.x;
    float s = B3[j];
#pragma unroll
    for (int i = 0; i < 10; ++i) s += y2[i] * W3[i * 10 + j];
    out[b * 10 + j] = s;
  }
}

extern "C" void kernel_launch(void* const* d_in, const int* in_sizes, int n_in,
                              void* d_out, int out_size, void* d_ws, size_t ws_size,
                              hipStream_t stream) {
  const int*   inp = (const int*)d_in[0];
  const float* cw1 = (const float*)d_in[1];
  const float* cb1 = (const float*)d_in[2];
  const float* cw2 = (const float*)d_in[3];
  const float* cb2 = (const float*)d_in[4];
  const float* cw3 = (const float*)d_in[5];
  const float* cb3 = (const float*)d_in[6];
  const float* a1K = (const float*)d_in[7];
  const float* a1Q = (const float*)d_in[8];
  const float* a1V = (const float*)d_in[9];
  const float* a2K = (const float*)d_in[10];
  const float* a2Q = (const float*)d_in[11];
  const float* a2V = (const float*)d_in[12];
  const float* a3K = (const float*)d_in[13];
  const float* a3Q = (const float*)d_in[14];
  const float* a3V = (const float*)d_in[15];
  const float* dw1 = (const float*)d_in[16];
  const float* db1 = (const float*)d_in[17];
  const float* dw2 = (const float*)d_in[18];
  const float* db2 = (const float*)d_in[19];
  const float* dw3 = (const float*)d_in[20];
  const float* db3 = (const float*)d_in[21];
  float* outp = (float*)d_out;

  // workspace layout (float units, 9,175,040 floats = 36.7 MB as before)
  float* wsf = (float*)d_ws;
  float*    c1   = wsf;                         // [B,4,4096,5]   [0 .. 5,242,880)
  float*    c2   = wsf + 5242880;               // [B,4,2048,5]   [5,242,880 .. 7,864,320)
  float*    x    = wsf + 7864320;               // [B,S,20]       [7,864,320 .. 9,175,040)
  ushort_t* qb   = (ushort_t*)(wsf);            // [B,S,32] bf16  [0 .. 1,048,576) fl
  ushort_t* kb   = (ushort_t*)(wsf + 1048576);  //                [1,048,576 .. 2,097,152)
  ushort_t* vt   = (ushort_t*)(wsf + 2097152);  // [B,32,S] bf16  [2,097,152 .. 3,145,728)
  float*    o    = wsf + 3145728;               // [B,S,20]       [3,145,728 .. 4,456,448)
  float*    part = wsf + 4456448;               // [64,4,10]      2,560 floats
  float*    w1t  = wsf + 4459008;               // [10, 20480]    204,800 floats

  conv1_kernel<<<1024, 256, 0, stream>>>(inp, cw1, cb1, c1);
  conv5_kernel<4096, false><<<512, 256, 0, stream>>>(c1, cw2, cb2, c2);
  conv5_kernel<2048, true><<<256, 256, 0, stream>>>(c2, cw3, cb3, x);
  // c1 dead from here; qb/kb/vt/o live in its footprint.
  transpose_w1<<<800, 256, 0, stream>>>(dw1, w1t);   // independent; overlaps nothing but is tiny

  proj_kernel<<<256, 256, 0, stream>>>(x, a1K, a1Q, a1V, qb, kb, vt);
  attn_kernel<<<dim3(16, 64), 256, 0, stream>>>(qb, kb, vt, o);

  proj_kernel<<<256, 256, 0, stream>>>(o, a2K, a2Q, a2V, qb, kb, vt);
  attn_kernel<<<dim3(16, 64), 256, 0, stream>>>(qb, kb, vt, x);

  proj_kernel<<<256, 256, 0, stream>>>(x, a3K, a3Q, a3V, qb, kb, vt);
  attn_kernel<<<dim3(16, 64), 256, 0, stream>>>(qb, kb, vt, o);

  dense1_partial<<<dim3(64, 4), 256, 0, stream>>>(o, w1t, part);
  dense_final<<<64, 64, 0, stream>>>(part, db1, dw2, db2, dw3, db3, outp);
}